// Round 3
// baseline (407.083 us; speedup 1.0000x reference)
//
#include <hip/hip_runtime.h>
#include <hip/hip_bf16.h>
#include <stdint.h>

#define D_IN 4096
#define TOKENS 2048
#define NUM_LATENTS 65536
#define GROUP_DIM 64
#define GROUP_MUL 4
#define IN_GROUPS 64
#define OUT_GROUPS 1024
#define KMID 256   // k' = i*4 + m

typedef __attribute__((ext_vector_type(8))) short short8;
typedef __attribute__((ext_vector_type(4))) float f32x4;

struct alignas(8)  US4 { unsigned short v[4]; };
struct alignas(16) US8 { unsigned short v[8]; };

__device__ inline unsigned short f2bf(float f) {
    union { float f; unsigned u; } w{f};
    unsigned r = w.u + 0x7fffu + ((w.u >> 16) & 1u);  // RNE
    return (unsigned short)(r >> 16);
}

__device__ inline void gload_lds16(const void* g, void* l) {
    __builtin_amdgcn_global_load_lds(
        (const __attribute__((address_space(1))) void*)g,
        (__attribute__((address_space(3))) void*)l, 16, 0, 0);
}

// ts byte address swizzle for stage3: [y][k] bf16, k-contig rows of 512B.
// XOR y-bits 3..5 into byte-bits 4..6 -> conflict-free scalar writes, and
// preserves 16B-contiguity for k-octet reads (k0 multiple of 8).
__device__ inline int SWZ(int y, int k) {
    return ((y << 9) + (k << 1)) ^ (((y >> 3) & 7) << 4);
}

// ---------------- converts ----------------
__global__ void cvt_bf16(const float* __restrict__ s, unsigned short* __restrict__ d, int n4) {
    int i = blockIdx.x * blockDim.x + threadIdx.x;
    if (i < n4) {
        f32x4 v = *(const f32x4*)(s + (size_t)i * 4);
        US4 o;
        #pragma unroll
        for (int j = 0; j < 4; ++j) o.v[j] = f2bf(v[j]);
        *(US4*)(d + (size_t)i * 4) = o;
    }
}

// outer[o][m][i] f32 -> outerB[o][i*4+m] bf16
__global__ void cvt_outer_perm(const float* __restrict__ s, unsigned short* __restrict__ d) {
    int t = blockIdx.x * blockDim.x + threadIdx.x;
    int o = t >> 8, r = t & 255, m = r >> 6, i = r & 63;
    d[(o << 8) + i * 4 + m] = f2bf(s[t]);
}

// inner[m][i][x][y] f32 -> innT[m][i][y][x] bf16 (one 64x64 transpose per block)
__global__ __launch_bounds__(256) void cvt_inner(const float* __restrict__ s, unsigned short* __restrict__ d) {
    __shared__ float tl[64][65];
    const int blk = blockIdx.x;          // m*64+i
    const int tid = threadIdx.x;
    const float* src = s + (size_t)blk * 4096;
    #pragma unroll
    for (int p = 0; p < 4; ++p) {
        int idx = p * 1024 + tid * 4;
        int x = idx >> 6, y = idx & 63;
        f32x4 v = *(const f32x4*)(src + idx);
        #pragma unroll
        for (int j = 0; j < 4; ++j) tl[x][y + j] = v[j];
    }
    __syncthreads();
    unsigned short* dst = d + (size_t)blk * 4096;
    #pragma unroll
    for (int p = 0; p < 4; ++p) {
        int idx = p * 1024 + tid * 4;
        int y = idx >> 6, x = idx & 63;
        US4 o;
        #pragma unroll
        for (int j = 0; j < 4; ++j) o.v[j] = f2bf(tl[x + j][y]);
        *(US4*)(dst + idx) = o;
    }
}

// ---------------- stage 1: h = x @ W^T + b ----------------
__global__ __launch_bounds__(256) void gemm_pre(
    const unsigned short* __restrict__ A,   // x_bf  [2048][4096]
    const unsigned short* __restrict__ B,   // w_bf  [4096][4096]
    const float* __restrict__ bias,
    unsigned short* __restrict__ H)
{
    __shared__ unsigned short As[128 * 64];
    __shared__ unsigned short Bs[128 * 64];
    const int tid = threadIdx.x;
    const int lane = tid & 63;
    const int w = tid >> 6;
    const int wm = w >> 1, wn = w & 1;
    int bx = blockIdx.x;
    bx = (bx & 7) * 64 + (bx >> 3);   // XCD swizzle: XCD x -> n-tiles 4x..4x+3 (B panel 4MB = L2)
    const int m0 = (bx & 15) * 128;
    const int n0 = (bx >> 4) * 128;

    const int lr = lane & 15;
    const int lk = (lane >> 4) * 8;

    f32x4 acc[4][4] = {};

    for (int k0 = 0; k0 < D_IN; k0 += 64) {
        #pragma unroll
        for (int c = 0; c < 4; ++c) {
            int f = c * 2048 + tid * 8;
            int r = f >> 6, col = f & 63;
            gload_lds16(A + (size_t)(m0 + r) * D_IN + k0 + col, As + f);
            gload_lds16(B + (size_t)(n0 + r) * D_IN + k0 + col, Bs + f);
        }
        asm volatile("s_waitcnt vmcnt(0)" ::: "memory");
        __syncthreads();
        #pragma unroll
        for (int kk = 0; kk < 2; ++kk) {
            short8 a[4], b[4];
            #pragma unroll
            for (int mi = 0; mi < 4; ++mi)
                a[mi] = *(const short8*)(As + (wm * 64 + mi * 16 + lr) * 64 + kk * 32 + lk);
            #pragma unroll
            for (int ni = 0; ni < 4; ++ni)
                b[ni] = *(const short8*)(Bs + (wn * 64 + ni * 16 + lr) * 64 + kk * 32 + lk);
            #pragma unroll
            for (int mi = 0; mi < 4; ++mi)
                #pragma unroll
                for (int ni = 0; ni < 4; ++ni)
                    acc[mi][ni] = __builtin_amdgcn_mfma_f32_16x16x32_bf16(a[mi], b[ni], acc[mi][ni], 0, 0, 0);
        }
        __syncthreads();
    }

    const int rin = (lane >> 4) * 4;
    #pragma unroll
    for (int ni = 0; ni < 4; ++ni) {
        int col = n0 + wn * 64 + ni * 16 + lr;
        float bv = bias[col];
        #pragma unroll
        for (int mi = 0; mi < 4; ++mi) {
            #pragma unroll
            for (int j = 0; j < 4; ++j) {
                int row = m0 + wm * 64 + mi * 16 + rin + j;
                H[(size_t)row * D_IN + col] = f2bf(acc[mi][ni][j] + bv);
            }
        }
    }
}

// ---------------- stage 2: t[b][i*4+m][y] = sum_x h[b,i,x] innT[m,i,y,x] ---
__global__ __launch_bounds__(256) void stage2(
    const unsigned short* __restrict__ H,     // [2048][4096] bf16
    const unsigned short* __restrict__ IT,    // innT [4][64][64][64] bf16 ([m][i][y][x])
    unsigned short* __restrict__ T)           // [2048][256][64] bf16
{
    __shared__ unsigned short hs[64 * 64];    // [b][x], linear (gload_lds)
    __shared__ unsigned short it[4 * 64 * 64];// [m][y][x], linear
    const int tid = threadIdx.x;
    const int lane = tid & 63;
    const int w = tid >> 6;      // = m
    int bx = blockIdx.x;
    const int sw = (bx & 7) * 256 + (bx >> 3);  // XCD x -> i in [8x,8x+8): innT/h stripes L2-resident
    const int i = sw >> 5;
    const int b0 = (sw & 31) * 64;

    // hs: 8KB, 2 instrs per wave
    #pragma unroll
    for (int c = 0; c < 2; ++c) {
        int off = w * 2048 + c * 1024 + lane * 16;          // byte offset, lane*16 component
        int r = off >> 7, col = (off & 127) >> 1;
        gload_lds16(H + (size_t)(b0 + r) * D_IN + i * 64 + col, (char*)hs + off);
    }
    // it: 32KB, wave w loads m=w (8 instrs)
    #pragma unroll
    for (int c = 0; c < 8; ++c) {
        int off = w * 8192 + c * 1024 + lane * 16;
        int rel = c * 1024 + lane * 16;
        int y = rel >> 7, x = (rel & 127) >> 1;
        gload_lds16(IT + ((size_t)(w * 64 + i)) * 4096 + y * 64 + x, (char*)it + off);
    }
    asm volatile("s_waitcnt vmcnt(0)" ::: "memory");
    __syncthreads();

    const int lr = lane & 15;
    const int lk = (lane >> 4) * 8;
    f32x4 acc[4][4] = {};
    #pragma unroll
    for (int kk = 0; kk < 2; ++kk) {
        short8 a[4], b[4];
        #pragma unroll
        for (int mi = 0; mi < 4; ++mi)
            a[mi] = *(const short8*)(hs + (mi * 16 + lr) * 64 + kk * 32 + lk);
        #pragma unroll
        for (int ni = 0; ni < 4; ++ni)
            b[ni] = *(const short8*)(it + w * 4096 + (ni * 16 + lr) * 64 + kk * 32 + lk);
        #pragma unroll
        for (int mi = 0; mi < 4; ++mi)
            #pragma unroll
            for (int ni = 0; ni < 4; ++ni)
                acc[mi][ni] = __builtin_amdgcn_mfma_f32_16x16x32_bf16(a[mi], b[ni], acc[mi][ni], 0, 0, 0);
    }

    const int rin = (lane >> 4) * 4;
    const int kp = i * 4 + w;
    #pragma unroll
    for (int mi = 0; mi < 4; ++mi) {
        #pragma unroll
        for (int ni = 0; ni < 4; ++ni) {
            int y = ni * 16 + lr;
            #pragma unroll
            for (int j = 0; j < 4; ++j) {
                int bb = b0 + mi * 16 + rin + j;
                T[((size_t)bb * KMID + kp) * 64 + y] = f2bf(acc[mi][ni][j]);
            }
        }
    }
}

// ---------------- stage 3: out[b][o][y] = sum_k outerB[o][k] * t[b][k][y]
// one block per token (512 thr, 8 waves x 128 o). t^T staged in swizzled LDS.
// MFMA operands swapped (A = t^T, B = outer) -> D[y][o], f32x4 y-contig stores.
__global__ __launch_bounds__(512) void stage3(
    const unsigned short* __restrict__ T,   // [2048][256][64] bf16
    const unsigned short* __restrict__ Ob,  // [1024][256] bf16
    float* __restrict__ out)                // [2048][65536] f32
{
    __shared__ char ts[32768];
    const int tid = threadIdx.x;
    const int lane = tid & 63;
    const int w = tid >> 6;
    int bx = blockIdx.x;
    const int b = (bx & 7) * 256 + (bx >> 3);   // XCD swizzle: contiguous T stream per XCD
    const int lr = lane & 15;
    const int hi = lane >> 4;

    // stage t_b [k][y] -> LDS transposed [y][k] with SWZ (conflict-free writes)
    {
        const unsigned short* src = T + (size_t)b * (KMID * 64);
        #pragma unroll
        for (int c = 0; c < 4; ++c) {
            int e = c * 4096 + tid * 8;
            int k = e >> 6, y = e & 63;     // y multiple of 8
            US8 v = *(const US8*)(src + e);
            #pragma unroll
            for (int j = 0; j < 8; ++j)
                *(unsigned short*)(ts + SWZ(y + j, k)) = v.v[j];
        }
    }
    __syncthreads();

    const int o_base = w * 128;
    f32x4 acc[4][8] = {};   // [ni_y][mi_o]
    for (int kt = 0; kt < 8; ++kt) {
        short8 tf[4], of[8];
        #pragma unroll
        for (int ni = 0; ni < 4; ++ni)
            tf[ni] = *(const short8*)(ts + SWZ(ni * 16 + lr, kt * 32 + hi * 8));
        #pragma unroll
        for (int mi = 0; mi < 8; ++mi)
            of[mi] = *(const short8*)(Ob + ((size_t)(o_base + mi * 16 + lr) << 8) + kt * 32 + hi * 8);
        #pragma unroll
        for (int ni = 0; ni < 4; ++ni)
            #pragma unroll
            for (int mi = 0; mi < 8; ++mi)
                acc[ni][mi] = __builtin_amdgcn_mfma_f32_16x16x32_bf16(tf[ni], of[mi], acc[ni][mi], 0, 0, 0);
    }

    float* ob = out + (size_t)b * NUM_LATENTS;
    #pragma unroll
    for (int ni = 0; ni < 4; ++ni) {
        #pragma unroll
        for (int mi = 0; mi < 8; ++mi) {
            int o = o_base + mi * 16 + lr;
            int y = ni * 16 + hi * 4;
            *(f32x4*)(ob + (o << 6) + y) = acc[ni][mi];   // full 64B sectors
        }
    }
}

extern "C" void kernel_launch(void* const* d_in, const int* in_sizes, int n_in,
                              void* d_out, int out_size, void* d_ws, size_t ws_size,
                              hipStream_t stream) {
    const float* x     = (const float*)d_in[0];
    const float* pre_w = (const float*)d_in[1];
    const float* pre_b = (const float*)d_in[2];
    const float* inner = (const float*)d_in[3];
    const float* outer = (const float*)d_in[4];
    float* out = (float*)d_out;

    char* ws = (char*)d_ws;
    unsigned short* x_bf = (unsigned short*)ws;  ws += (size_t)TOKENS * D_IN * 2;
    unsigned short* w_bf = (unsigned short*)ws;  ws += (size_t)D_IN * D_IN * 2;
    unsigned short* o_bf = (unsigned short*)ws;  ws += (size_t)OUT_GROUPS * KMID * 2;
    unsigned short* h_bf = (unsigned short*)ws;  ws += (size_t)TOKENS * D_IN * 2;
    unsigned short* t_bf = (unsigned short*)ws;  ws += (size_t)TOKENS * KMID * 64 * 2;
    unsigned short* it_bf = (unsigned short*)ws; ws += (size_t)GROUP_MUL * IN_GROUPS * 64 * 64 * 2;

    cvt_bf16<<<(TOKENS * D_IN / 4 + 255) / 256, 256, 0, stream>>>(x, x_bf, TOKENS * D_IN / 4);
    cvt_bf16<<<(D_IN * D_IN / 4 + 255) / 256, 256, 0, stream>>>(pre_w, w_bf, D_IN * D_IN / 4);
    cvt_outer_perm<<<OUT_GROUPS * KMID / 256, 256, 0, stream>>>(outer, o_bf);
    cvt_inner<<<GROUP_MUL * IN_GROUPS, 256, 0, stream>>>(inner, it_bf);

    gemm_pre<<<512, 256, 0, stream>>>(x_bf, w_bf, pre_b, h_bf);
    stage2<<<2048, 256, 0, stream>>>(h_bf, it_bf, t_bf);
    stage3<<<2048, 512, 0, stream>>>(t_bf, o_bf, out);
}

// Round 4
// 381.615 us; speedup vs baseline: 1.0667x; 1.0667x over previous
//
#include <hip/hip_runtime.h>
#include <hip/hip_bf16.h>
#include <stdint.h>

#define D_IN 4096
#define TOKENS 2048
#define NUM_LATENTS 65536
#define GROUP_DIM 64
#define GROUP_MUL 4
#define IN_GROUPS 64
#define OUT_GROUPS 1024
#define KMID 256   // k' = i*4 + m

typedef __attribute__((ext_vector_type(8))) short short8;
typedef __attribute__((ext_vector_type(4))) float f32x4;

struct alignas(8)  US4 { unsigned short v[4]; };
struct alignas(16) US8 { unsigned short v[8]; };

__device__ inline unsigned short f2bf(float f) {
    union { float f; unsigned u; } w{f};
    unsigned r = w.u + 0x7fffu + ((w.u >> 16) & 1u);  // RNE
    return (unsigned short)(r >> 16);
}

__device__ inline void gload_lds16(const void* g, void* l) {
    __builtin_amdgcn_global_load_lds(
        (const __attribute__((address_space(1))) void*)g,
        (__attribute__((address_space(3))) void*)l, 16, 0, 0);
}

// stage3 LDS swizzle: [y][k] bf16 rows of 512B; XOR y-bits 3..5 into byte 4..6
__device__ inline int SWZ(int y, int k) {
    return ((y << 9) + (k << 1)) ^ (((y >> 3) & 7) << 4);
}

// ---------------- fused converts: w, x (vector), outer (perm) -------------
__global__ void cvt_all(const float* __restrict__ w, const float* __restrict__ x,
                        const float* __restrict__ outer,
                        unsigned short* __restrict__ w_bf, unsigned short* __restrict__ x_bf,
                        unsigned short* __restrict__ o_bf) {
    int s = blockIdx.x * blockDim.x + threadIdx.x;   // f32x4 slot
    if (s < 4194304) {                               // w: 16.8M elems
        f32x4 v = *(const f32x4*)(w + (size_t)s * 4);
        US4 o;
        #pragma unroll
        for (int j = 0; j < 4; ++j) o.v[j] = f2bf(v[j]);
        *(US4*)(w_bf + (size_t)s * 4) = o;
    } else if (s < 6291456) {                        // x: 8.4M elems
        int t = s - 4194304;
        f32x4 v = *(const f32x4*)(x + (size_t)t * 4);
        US4 o;
        #pragma unroll
        for (int j = 0; j < 4; ++j) o.v[j] = f2bf(v[j]);
        *(US4*)(x_bf + (size_t)t * 4) = o;
    } else if (s < 6356992) {                        // outer: perm [o][m][i]->[o][i*4+m]
        int t0 = (s - 6291456) * 4;
        int o = t0 >> 8, r = t0 & 255, m = r >> 6, i = r & 63;
        f32x4 v = *(const f32x4*)(outer + t0);
        #pragma unroll
        for (int j = 0; j < 4; ++j)
            o_bf[(o << 8) + (i + j) * 4 + m] = f2bf(v[j]);
    }
}

// inner[m][i][x][y] f32 -> innT[m][i][y][x^((y&7)<<3)] bf16 (pre-swizzled)
__global__ __launch_bounds__(256) void cvt_inner(const float* __restrict__ s, unsigned short* __restrict__ d) {
    __shared__ float tl[64][65];
    const int blk = blockIdx.x;          // m*64+i
    const int tid = threadIdx.x;
    const float* src = s + (size_t)blk * 4096;
    #pragma unroll
    for (int p = 0; p < 4; ++p) {
        int idx = p * 1024 + tid * 4;
        int x = idx >> 6, y = idx & 63;
        f32x4 v = *(const f32x4*)(src + idx);
        #pragma unroll
        for (int j = 0; j < 4; ++j) tl[x][y + j] = v[j];
    }
    __syncthreads();
    unsigned short* dst = d + (size_t)blk * 4096;
    #pragma unroll
    for (int p = 0; p < 4; ++p) {
        int idx = p * 1024 + tid * 4;
        int y = idx >> 6, x0 = idx & 63;
        US4 o;
        #pragma unroll
        for (int j = 0; j < 4; ++j) o.v[j] = f2bf(tl[x0 + j][y]);
        *(US4*)(dst + y * 64 + (x0 ^ ((y & 7) << 3))) = o;
    }
}

// ------- fused stage 1+2: h = x@W^T+b (regs) -> t[b][i*4+m][y] ------------
__global__ __launch_bounds__(256) void gemm_fused(
    const unsigned short* __restrict__ A,   // x_bf  [2048][4096]
    const unsigned short* __restrict__ B,   // w_bf  [4096][4096]
    const float* __restrict__ bias,
    const unsigned short* __restrict__ IT,  // innT [4][64][64][64] bf16, x pre-swizzled
    unsigned short* __restrict__ T)         // [2048][256][64] bf16
{
    __shared__ unsigned short smem[24576];  // As 0..8191 | Bs 8192..16383 | inn 16384..24575
    unsigned short* As = smem;              // h tile overlays As+Bs after main loop
    unsigned short* Bs = smem + 8192;
    unsigned short* inn = smem + 16384;

    const int tid = threadIdx.x;
    const int lane = tid & 63;
    const int w = tid >> 6;
    const int wm = w >> 1, wn = w & 1;
    int bx = blockIdx.x;
    bx = (bx & 7) * 64 + (bx >> 3);   // XCD swizzle: B panel 4MB = one L2
    const int m0 = (bx & 15) * 128;
    const int n0 = (bx >> 4) * 128;
    const int i0 = n0 >> 6;           // first of 2 i-groups this block owns

    const int lr = lane & 15;
    const int lk = (lane >> 4) * 8;
    const int rin = (lane >> 4) * 4;

    f32x4 acc[4][4] = {};

    for (int k0 = 0; k0 < D_IN; k0 += 64) {
        #pragma unroll
        for (int c = 0; c < 4; ++c) {
            int f = c * 2048 + tid * 8;
            int r = f >> 6, col = f & 63;
            gload_lds16(A + (size_t)(m0 + r) * D_IN + k0 + col, As + f);
            gload_lds16(B + (size_t)(n0 + r) * D_IN + k0 + col, Bs + f);
        }
        asm volatile("s_waitcnt vmcnt(0)" ::: "memory");
        __syncthreads();
        #pragma unroll
        for (int kk = 0; kk < 2; ++kk) {
            short8 a[4], b[4];
            #pragma unroll
            for (int mi = 0; mi < 4; ++mi)
                a[mi] = *(const short8*)(As + (wm * 64 + mi * 16 + lr) * 64 + kk * 32 + lk);
            #pragma unroll
            for (int ni = 0; ni < 4; ++ni)
                b[ni] = *(const short8*)(Bs + (wn * 64 + ni * 16 + lr) * 64 + kk * 32 + lk);
            #pragma unroll
            for (int mi = 0; mi < 4; ++mi)
                #pragma unroll
                for (int ni = 0; ni < 4; ++ni)
                    acc[mi][ni] = __builtin_amdgcn_mfma_f32_16x16x32_bf16(a[mi], b[ni], acc[mi][ni], 0, 0, 0);
        }
        __syncthreads();
    }

    // ---- epilogue A: write h (+bias, bf16) into smem[0..16383] swizzled ----
    // h[tok][col] at elem tok*128 + (col ^ ((tok&7)<<3)), tok/col local 0..127
    #pragma unroll
    for (int ni = 0; ni < 4; ++ni) {
        int col = wn * 64 + ni * 16 + lr;
        float bv = bias[n0 + col];
        #pragma unroll
        for (int mi = 0; mi < 4; ++mi) {
            #pragma unroll
            for (int j = 0; j < 4; ++j) {
                int tok = wm * 64 + mi * 16 + rin + j;
                smem[tok * 128 + (col ^ ((tok & 7) << 3))] = f2bf(acc[mi][ni][j] + bv);
            }
        }
    }

    // ---- epilogue B: per m, t[tok][i*4+m][y] = sum_x h[tok][i,x] innT[m,i,y,x]
    for (int m = 0; m < 4; ++m) {
        // load innT[m][i0..i0+1] -> inn (16 KB, linear; global is pre-swizzled)
        #pragma unroll
        for (int c = 0; c < 4; ++c) {
            int e = c * 2048 + tid * 8;                // elem offset in inn region
            int i_loc = e >> 12, rem = e & 4095;
            gload_lds16(IT + ((size_t)(m * 64 + i0 + i_loc) << 12) + rem, inn + e);
        }
        asm volatile("s_waitcnt vmcnt(0)" ::: "memory");
        __syncthreads();   // inn ready AND (m==0) h visible

        f32x4 acc2[4][4] = {};
        #pragma unroll
        for (int kk = 0; kk < 2; ++kk) {
            short8 a[4], b2[4];
            #pragma unroll
            for (int mi = 0; mi < 4; ++mi) {
                int tok = wm * 64 + mi * 16 + lr;
                a[mi] = *(const short8*)(smem + tok * 128 + ((wn * 64 + kk * 32 + lk) ^ ((tok & 7) << 3)));
            }
            #pragma unroll
            for (int ni = 0; ni < 4; ++ni) {
                int y = ni * 16 + lr;
                b2[ni] = *(const short8*)(inn + wn * 4096 + y * 64 + ((kk * 32 + lk) ^ ((y & 7) << 3)));
            }
            #pragma unroll
            for (int mi = 0; mi < 4; ++mi)
                #pragma unroll
                for (int ni = 0; ni < 4; ++ni)
                    acc2[mi][ni] = __builtin_amdgcn_mfma_f32_16x16x32_bf16(a[mi], b2[ni], acc2[mi][ni], 0, 0, 0);
        }

        const int kp = (i0 + wn) * 4 + m;
        #pragma unroll
        for (int mi = 0; mi < 4; ++mi) {
            #pragma unroll
            for (int ni = 0; ni < 4; ++ni) {
                int y = ni * 16 + lr;
                #pragma unroll
                for (int j = 0; j < 4; ++j) {
                    int tok = m0 + wm * 64 + mi * 16 + rin + j;
                    T[((size_t)tok * KMID + kp) * 64 + y] = f2bf(acc2[mi][ni][j]);
                }
            }
        }
        __syncthreads();   // protect inn before next m's DMA
    }
}

// ---------------- stage 3: out[b][o][y] = sum_k outerB[o][k] * t[b][k][y] --
__global__ __launch_bounds__(512) void stage3(
    const unsigned short* __restrict__ T,   // [2048][256][64] bf16
    const unsigned short* __restrict__ Ob,  // [1024][256] bf16
    float* __restrict__ out)                // [2048][65536] f32
{
    __shared__ char ts[32768];
    const int tid = threadIdx.x;
    const int lane = tid & 63;
    const int w = tid >> 6;
    int bx = blockIdx.x;
    const int b = (bx & 7) * 256 + (bx >> 3);   // XCD swizzle
    const int lr = lane & 15;
    const int hi = lane >> 4;

    {
        const unsigned short* src = T + (size_t)b * (KMID * 64);
        #pragma unroll
        for (int c = 0; c < 4; ++c) {
            int e = c * 4096 + tid * 8;
            int k = e >> 6, y = e & 63;
            US8 v = *(const US8*)(src + e);
            #pragma unroll
            for (int j = 0; j < 8; ++j)
                *(unsigned short*)(ts + SWZ(y + j, k)) = v.v[j];
        }
    }
    __syncthreads();

    const int o_base = w * 128;
    f32x4 acc[4][8] = {};
    for (int kt = 0; kt < 8; ++kt) {
        short8 tf[4], of[8];
        #pragma unroll
        for (int ni = 0; ni < 4; ++ni)
            tf[ni] = *(const short8*)(ts + SWZ(ni * 16 + lr, kt * 32 + hi * 8));
        #pragma unroll
        for (int mi = 0; mi < 8; ++mi)
            of[mi] = *(const short8*)(Ob + ((size_t)(o_base + mi * 16 + lr) << 8) + kt * 32 + hi * 8);
        #pragma unroll
        for (int ni = 0; ni < 4; ++ni)
            #pragma unroll
            for (int mi = 0; mi < 8; ++mi)
                acc[ni][mi] = __builtin_amdgcn_mfma_f32_16x16x32_bf16(tf[ni], of[mi], acc[ni][mi], 0, 0, 0);
    }

    float* ob = out + (size_t)b * NUM_LATENTS;
    #pragma unroll
    for (int ni = 0; ni < 4; ++ni) {
        #pragma unroll
        for (int mi = 0; mi < 8; ++mi) {
            int o = o_base + mi * 16 + lr;
            int y = ni * 16 + hi * 4;
            *(f32x4*)(ob + (o << 6) + y) = acc[ni][mi];
        }
    }
}

extern "C" void kernel_launch(void* const* d_in, const int* in_sizes, int n_in,
                              void* d_out, int out_size, void* d_ws, size_t ws_size,
                              hipStream_t stream) {
    const float* x     = (const float*)d_in[0];
    const float* pre_w = (const float*)d_in[1];
    const float* pre_b = (const float*)d_in[2];
    const float* inner = (const float*)d_in[3];
    const float* outer = (const float*)d_in[4];
    float* out = (float*)d_out;

    char* ws = (char*)d_ws;
    unsigned short* x_bf = (unsigned short*)ws;  ws += (size_t)TOKENS * D_IN * 2;
    unsigned short* w_bf = (unsigned short*)ws;  ws += (size_t)D_IN * D_IN * 2;
    unsigned short* o_bf = (unsigned short*)ws;  ws += (size_t)OUT_GROUPS * KMID * 2;
    unsigned short* t_bf = (unsigned short*)ws;  ws += (size_t)TOKENS * KMID * 64 * 2;
    unsigned short* it_bf = (unsigned short*)ws; ws += (size_t)GROUP_MUL * IN_GROUPS * 64 * 64 * 2;

    cvt_all<<<(6356992 + 255) / 256, 256, 0, stream>>>(pre_w, x, outer, w_bf, x_bf, o_bf);
    cvt_inner<<<GROUP_MUL * IN_GROUPS, 256, 0, stream>>>(inner, it_bf);

    gemm_fused<<<512, 256, 0, stream>>>(x_bf, w_bf, pre_b, it_bf, t_bf);
    stage3<<<2048, 512, 0, stream>>>(t_bf, o_bf, out);
}

// Round 5
// 327.100 us; speedup vs baseline: 1.2445x; 1.1667x over previous
//
#include <hip/hip_runtime.h>
#include <hip/hip_bf16.h>
#include <stdint.h>

#define D_IN 4096
#define TOKENS 2048
#define NUM_LATENTS 65536
#define GROUP_DIM 64
#define GROUP_MUL 4
#define IN_GROUPS 64
#define OUT_GROUPS 1024
#define KMID 256   // k' = i*4 + m

typedef __attribute__((ext_vector_type(8))) short short8;
typedef __attribute__((ext_vector_type(4))) float f32x4;

struct alignas(8)  US4 { unsigned short v[4]; };

#define FLAT_BLOCKS 24832   // (4194304 + 2097152 + 65536) / 256

__device__ inline unsigned short f2bf(float f) {
    union { float f; unsigned u; } w{f};
    unsigned r = w.u + 0x7fffu + ((w.u >> 16) & 1u);  // RNE
    return (unsigned short)(r >> 16);
}

__device__ inline void gload_lds16(const void* g, void* l) {
    __builtin_amdgcn_global_load_lds(
        (const __attribute__((address_space(1))) void*)g,
        (__attribute__((address_space(3))) void*)l, 16, 0, 0);
}

// stage3 LDS swizzle: [y][k] bf16 rows of 512B; XOR y-bits 3..5 into byte 4..6
__device__ inline int SWZ(int y, int k) {
    return ((y << 9) + (k << 1)) ^ (((y >> 3) & 7) << 4);
}

// ------------- merged converts: w, x (vector), outer (perm), inner (transpose)
__global__ __launch_bounds__(256) void cvt_all(
    const float* __restrict__ w, const float* __restrict__ x,
    const float* __restrict__ outer, const float* __restrict__ inner,
    unsigned short* __restrict__ w_bf, unsigned short* __restrict__ x_bf,
    unsigned short* __restrict__ o_bf, unsigned short* __restrict__ it_bf) {
    __shared__ float tl[64][65];
    int blk = blockIdx.x;
    const int tid = threadIdx.x;
    if (blk >= FLAT_BLOCKS) {
        // inner[m][i][x][y] f32 -> innT[m][i][y][x^((y&7)<<3)] bf16 (pre-swizzled)
        blk -= FLAT_BLOCKS;                  // m*64+i
        const float* src = inner + (size_t)blk * 4096;
        #pragma unroll
        for (int p = 0; p < 4; ++p) {
            int idx = p * 1024 + tid * 4;
            int xx = idx >> 6, y = idx & 63;
            f32x4 v = *(const f32x4*)(src + idx);
            #pragma unroll
            for (int j = 0; j < 4; ++j) tl[xx][y + j] = v[j];
        }
        __syncthreads();
        unsigned short* dst = it_bf + (size_t)blk * 4096;
        #pragma unroll
        for (int p = 0; p < 4; ++p) {
            int idx = p * 1024 + tid * 4;
            int y = idx >> 6, x0 = idx & 63;
            US4 o;
            #pragma unroll
            for (int j = 0; j < 4; ++j) o.v[j] = f2bf(tl[x0 + j][y]);
            *(US4*)(dst + y * 64 + (x0 ^ ((y & 7) << 3))) = o;
        }
        return;
    }
    int s = blk * 256 + tid;                 // f32x4 slot
    if (s < 4194304) {                       // w
        f32x4 v = *(const f32x4*)(w + (size_t)s * 4);
        US4 o;
        #pragma unroll
        for (int j = 0; j < 4; ++j) o.v[j] = f2bf(v[j]);
        *(US4*)(w_bf + (size_t)s * 4) = o;
    } else if (s < 6291456) {                // x
        int t = s - 4194304;
        f32x4 v = *(const f32x4*)(x + (size_t)t * 4);
        US4 o;
        #pragma unroll
        for (int j = 0; j < 4; ++j) o.v[j] = f2bf(v[j]);
        *(US4*)(x_bf + (size_t)t * 4) = o;
    } else {                                 // outer: [o][m][i] -> [o][i*4+m]
        int t0 = (s - 6291456) * 4;
        int o = t0 >> 8, r = t0 & 255, m = r >> 6, i = r & 63;
        f32x4 v = *(const f32x4*)(outer + t0);
        #pragma unroll
        for (int j = 0; j < 4; ++j)
            o_bf[(o << 8) + (i + j) * 4 + m] = f2bf(v[j]);
    }
}

// ------- fused stage 1+2: h = x@W^T+b (regs) -> t[b][i*4+m][y] ------------
// Double-buffered LDS + counted vmcnt(8) pipeline; MFMA operands swapped so
// D=[col][tok] -> each thread holds 4 consecutive cols -> US4 8B stores.
__global__ __launch_bounds__(256, 2) void gemm_fused(
    const unsigned short* __restrict__ A,   // x_bf  [2048][4096]
    const unsigned short* __restrict__ B,   // w_bf  [4096][4096]
    const float* __restrict__ bias,
    const unsigned short* __restrict__ IT,  // innT [4][64][64][64] bf16, x pre-swizzled
    unsigned short* __restrict__ T)         // [2048][256][64] bf16
{
    // As0[0..8191] Bs0[..16383] As1[..24575] Bs1[..32767] | inn[32768..40959]
    // h tile (128x128=16384 elems) overlays As0+Bs0 after the main loop.
    __shared__ unsigned short smem[40960];  // 80 KB -> 2 blocks/CU
    unsigned short* inn = smem + 32768;

    const int tid = threadIdx.x;
    const int lane = tid & 63;
    const int w = tid >> 6;
    const int wm = w >> 1, wn = w & 1;
    int bx = blockIdx.x;
    bx = (bx & 7) * 64 + (bx >> 3);   // XCD swizzle: B panel 4MB = one L2
    const int m0 = (bx & 15) * 128;
    const int n0 = (bx >> 4) * 128;
    const int i0 = n0 >> 6;

    const int lr = lane & 15;
    const int hi = lane >> 4;
    const int lk = hi * 8;

    f32x4 acc[4][4] = {};

    auto STAGE = [&](int buf, int k0) {
        #pragma unroll
        for (int c = 0; c < 4; ++c) {
            int f = c * 2048 + tid * 8;
            int r = f >> 6, col = f & 63;
            gload_lds16(A + (size_t)(m0 + r) * D_IN + k0 + col, smem + buf * 16384 + f);
            gload_lds16(B + (size_t)(n0 + r) * D_IN + k0 + col, smem + buf * 16384 + 8192 + f);
        }
    };
    auto COMPUTE = [&](int buf) {
        const unsigned short* as = smem + buf * 16384;
        const unsigned short* bs = as + 8192;
        #pragma unroll
        for (int kk = 0; kk < 2; ++kk) {
            short8 a[4], b[4];
            #pragma unroll
            for (int mi = 0; mi < 4; ++mi)
                a[mi] = *(const short8*)(as + (wm * 64 + mi * 16 + lr) * 64 + kk * 32 + lk);
            #pragma unroll
            for (int ni = 0; ni < 4; ++ni)
                b[ni] = *(const short8*)(bs + (wn * 64 + ni * 16 + lr) * 64 + kk * 32 + lk);
            #pragma unroll
            for (int mi = 0; mi < 4; ++mi)
                #pragma unroll
                for (int ni = 0; ni < 4; ++ni)   // swapped: D=[col][tok]
                    acc[mi][ni] = __builtin_amdgcn_mfma_f32_16x16x32_bf16(b[ni], a[mi], acc[mi][ni], 0, 0, 0);
        }
    };

    STAGE(0, 0);
    #pragma unroll 1
    for (int t = 0; t < 63; ++t) {
        STAGE((t + 1) & 1, (t + 1) * 64);
        asm volatile("s_waitcnt vmcnt(8)" ::: "memory");   // cur tile landed, next in flight
        __builtin_amdgcn_s_barrier();
        __builtin_amdgcn_sched_barrier(0);
        COMPUTE(t & 1);
        __builtin_amdgcn_s_barrier();                      // all reads done before next STAGE
        __builtin_amdgcn_sched_barrier(0);
    }
    asm volatile("s_waitcnt vmcnt(0)" ::: "memory");
    __builtin_amdgcn_s_barrier();
    __builtin_amdgcn_sched_barrier(0);
    COMPUTE(1);

    // ---- epilogue A: h (+bias, bf16) -> smem[0..16383], swizzled, US4 stores
    #pragma unroll
    for (int ni = 0; ni < 4; ++ni) {
        int col0 = wn * 64 + ni * 16 + hi * 4;
        f32x4 bv = *(const f32x4*)(bias + n0 + col0);
        #pragma unroll
        for (int mi = 0; mi < 4; ++mi) {
            int tok = wm * 64 + mi * 16 + lr;
            US4 o;
            #pragma unroll
            for (int j = 0; j < 4; ++j) o.v[j] = f2bf(acc[mi][ni][j] + bv[j]);
            *(US4*)(smem + tok * 128 + (col0 ^ ((tok & 7) << 3))) = o;
        }
    }

    // ---- epilogue B: per m, t[tok][(i0+wn)*4+m][y] = h[tok][i,:] @ innT^T
    for (int m = 0; m < 4; ++m) {
        #pragma unroll
        for (int c = 0; c < 4; ++c) {
            int e = c * 2048 + tid * 8;
            int i_loc = e >> 12, rem = e & 4095;
            gload_lds16(IT + ((size_t)(m * 64 + i0 + i_loc) << 12) + rem, inn + e);
        }
        asm volatile("s_waitcnt vmcnt(0)" ::: "memory");
        __syncthreads();   // inn ready; (m==0) h visible

        f32x4 acc2[4][4] = {};
        #pragma unroll
        for (int kk = 0; kk < 2; ++kk) {
            short8 a[4], b2[4];
            #pragma unroll
            for (int mi = 0; mi < 4; ++mi) {
                int tok = wm * 64 + mi * 16 + lr;
                a[mi] = *(const short8*)(smem + tok * 128 + ((wn * 64 + kk * 32 + lk) ^ ((tok & 7) << 3)));
            }
            #pragma unroll
            for (int ni = 0; ni < 4; ++ni) {
                int y = ni * 16 + lr;
                b2[ni] = *(const short8*)(inn + wn * 4096 + y * 64 + ((kk * 32 + lk) ^ ((y & 7) << 3)));
            }
            #pragma unroll
            for (int mi = 0; mi < 4; ++mi)
                #pragma unroll
                for (int ni = 0; ni < 4; ++ni)   // swapped: D=[y][tok]
                    acc2[mi][ni] = __builtin_amdgcn_mfma_f32_16x16x32_bf16(b2[ni], a[mi], acc2[mi][ni], 0, 0, 0);
        }

        const int kp = (i0 + wn) * 4 + m;
        #pragma unroll
        for (int mi = 0; mi < 4; ++mi) {
            int tok = m0 + wm * 64 + mi * 16 + lr;
            unsigned short* trow = T + ((size_t)tok * KMID + kp) * 64;
            #pragma unroll
            for (int ni = 0; ni < 4; ++ni) {
                int y0 = ni * 16 + hi * 4;
                US4 o;
                #pragma unroll
                for (int j = 0; j < 4; ++j) o.v[j] = f2bf(acc2[mi][ni][j]);
                *(US4*)(trow + y0) = o;
            }
        }
        __syncthreads();   // protect inn before next m's DMA
    }
}

// ---------------- stage 3: out[b][o][y] = sum_k outerB[o][k] * t[b][k][y] --
__global__ __launch_bounds__(512) void stage3(
    const unsigned short* __restrict__ T,   // [2048][256][64] bf16
    const unsigned short* __restrict__ Ob,  // [1024][256] bf16
    float* __restrict__ out)                // [2048][65536] f32
{
    __shared__ char ts[32768];
    const int tid = threadIdx.x;
    const int lane = tid & 63;
    const int w = tid >> 6;
    int bx = blockIdx.x;
    const int b = (bx & 7) * 256 + (bx >> 3);   // XCD swizzle
    const int lr = lane & 15;
    const int hi = lane >> 4;

    {
        const unsigned short* src = T + (size_t)b * (KMID * 64);
        #pragma unroll
        for (int c = 0; c < 4; ++c) {
            int e = c * 4096 + tid * 8;
            int k = e >> 6, y = e & 63;
            short8 v = __builtin_nontemporal_load((const short8*)(src + e));
            #pragma unroll
            for (int j = 0; j < 8; ++j)
                *(unsigned short*)(ts + SWZ(y + j, k)) = (unsigned short)v[j];
        }
    }
    __syncthreads();

    const int o_base = w * 128;
    f32x4 acc[4][8] = {};
    for (int kt = 0; kt < 8; ++kt) {
        short8 tf[4], of[8];
        #pragma unroll
        for (int ni = 0; ni < 4; ++ni)
            tf[ni] = *(const short8*)(ts + SWZ(ni * 16 + lr, kt * 32 + hi * 8));
        #pragma unroll
        for (int mi = 0; mi < 8; ++mi)
            of[mi] = *(const short8*)(Ob + ((size_t)(o_base + mi * 16 + lr) << 8) + kt * 32 + hi * 8);
        #pragma unroll
        for (int ni = 0; ni < 4; ++ni)
            #pragma unroll
            for (int mi = 0; mi < 8; ++mi)
                acc[ni][mi] = __builtin_amdgcn_mfma_f32_16x16x32_bf16(tf[ni], of[mi], acc[ni][mi], 0, 0, 0);
    }

    float* ob = out + (size_t)b * NUM_LATENTS;
    #pragma unroll
    for (int ni = 0; ni < 4; ++ni) {
        #pragma unroll
        for (int mi = 0; mi < 8; ++mi) {
            int o = o_base + mi * 16 + lr;
            int y = ni * 16 + hi * 4;
            __builtin_nontemporal_store(acc[ni][mi], (f32x4*)(ob + (o << 6) + y));
        }
    }
}

extern "C" void kernel_launch(void* const* d_in, const int* in_sizes, int n_in,
                              void* d_out, int out_size, void* d_ws, size_t ws_size,
                              hipStream_t stream) {
    const float* x     = (const float*)d_in[0];
    const float* pre_w = (const float*)d_in[1];
    const float* pre_b = (const float*)d_in[2];
    const float* inner = (const float*)d_in[3];
    const float* outer = (const float*)d_in[4];
    float* out = (float*)d_out;

    char* ws = (char*)d_ws;
    unsigned short* x_bf = (unsigned short*)ws;  ws += (size_t)TOKENS * D_IN * 2;
    unsigned short* w_bf = (unsigned short*)ws;  ws += (size_t)D_IN * D_IN * 2;
    unsigned short* o_bf = (unsigned short*)ws;  ws += (size_t)OUT_GROUPS * KMID * 2;
    unsigned short* t_bf = (unsigned short*)ws;  ws += (size_t)TOKENS * KMID * 64 * 2;
    unsigned short* it_bf = (unsigned short*)ws; ws += (size_t)GROUP_MUL * IN_GROUPS * 64 * 64 * 2;

    cvt_all<<<FLAT_BLOCKS + GROUP_MUL * IN_GROUPS, 256, 0, stream>>>(
        pre_w, x, outer, inner, w_bf, x_bf, o_bf, it_bf);

    gemm_fused<<<512, 256, 0, stream>>>(x_bf, w_bf, pre_b, it_bf, t_bf);
    stage3<<<2048, 512, 0, stream>>>(t_bf, o_bf, out);
}

// Round 6
// 315.026 us; speedup vs baseline: 1.2922x; 1.0383x over previous
//
#include <hip/hip_runtime.h>
#include <hip/hip_bf16.h>
#include <stdint.h>

#define D_IN 4096
#define TOKENS 2048
#define NUM_LATENTS 65536
#define GROUP_DIM 64
#define GROUP_MUL 4
#define IN_GROUPS 64
#define OUT_GROUPS 1024
#define KMID 256   // k' = i*4 + m

typedef __attribute__((ext_vector_type(8))) short short8;
typedef __attribute__((ext_vector_type(4))) float f32x4;

struct alignas(8)  US4 { unsigned short v[4]; };

#define FLAT_BLOCKS 24832   // (4194304 + 2097152 + 65536) / 256

__device__ inline unsigned short f2bf(float f) {
    union { float f; unsigned u; } w{f};
    unsigned r = w.u + 0x7fffu + ((w.u >> 16) & 1u);  // RNE
    return (unsigned short)(r >> 16);
}

__device__ inline void gload_lds16(const void* g, void* l) {
    __builtin_amdgcn_global_load_lds(
        (const __attribute__((address_space(1))) void*)g,
        (__attribute__((address_space(3))) void*)l, 16, 0, 0);
}

// stage3 LDS swizzle: [y][k] bf16 rows of 512B.
// XOR ((y&7)^((y>>3)&7)) into byte bits 4..6 -> 2-way (free) on BOTH the
// scalar write side (y0=(tid&7)*8, j=y&7) and the tf read side (y=ni*16+lr).
__device__ inline int SWZ(int y, int k) {
    return ((y << 9) + (k << 1)) ^ ((((y & 7) ^ ((y >> 3) & 7)) << 4));
}

// ------------- merged converts: w, x (vector), outer (perm), inner (transpose)
__global__ __launch_bounds__(256) void cvt_all(
    const float* __restrict__ w, const float* __restrict__ x,
    const float* __restrict__ outer, const float* __restrict__ inner,
    unsigned short* __restrict__ w_bf, unsigned short* __restrict__ x_bf,
    unsigned short* __restrict__ o_bf, unsigned short* __restrict__ it_bf) {
    __shared__ float tl[64][65];
    int blk = blockIdx.x;
    const int tid = threadIdx.x;
    if (blk >= FLAT_BLOCKS) {
        // inner[m][i][x][y] f32 -> innT[m][i][y][x^((y&7)<<3)] bf16 (pre-swizzled)
        blk -= FLAT_BLOCKS;                  // m*64+i
        const float* src = inner + (size_t)blk * 4096;
        #pragma unroll
        for (int p = 0; p < 4; ++p) {
            int idx = p * 1024 + tid * 4;
            int xx = idx >> 6, y = idx & 63;
            f32x4 v = *(const f32x4*)(src + idx);
            #pragma unroll
            for (int j = 0; j < 4; ++j) tl[xx][y + j] = v[j];
        }
        __syncthreads();
        unsigned short* dst = it_bf + (size_t)blk * 4096;
        #pragma unroll
        for (int p = 0; p < 4; ++p) {
            int idx = p * 1024 + tid * 4;
            int y = idx >> 6, x0 = idx & 63;
            US4 o;
            #pragma unroll
            for (int j = 0; j < 4; ++j) o.v[j] = f2bf(tl[x0 + j][y]);
            *(US4*)(dst + y * 64 + (x0 ^ ((y & 7) << 3))) = o;
        }
        return;
    }
    int s = blk * 256 + tid;                 // f32x4 slot
    if (s < 4194304) {                       // w
        f32x4 v = *(const f32x4*)(w + (size_t)s * 4);
        US4 o;
        #pragma unroll
        for (int j = 0; j < 4; ++j) o.v[j] = f2bf(v[j]);
        *(US4*)(w_bf + (size_t)s * 4) = o;
    } else if (s < 6291456) {                // x
        int t = s - 4194304;
        f32x4 v = *(const f32x4*)(x + (size_t)t * 4);
        US4 o;
        #pragma unroll
        for (int j = 0; j < 4; ++j) o.v[j] = f2bf(v[j]);
        *(US4*)(x_bf + (size_t)t * 4) = o;
    } else {                                 // outer: [o][m][i] -> [o][i*4+m]
        int t0 = (s - 6291456) * 4;
        int o = t0 >> 8, r = t0 & 255, m = r >> 6, i = r & 63;
        f32x4 v = *(const f32x4*)(outer + t0);
        #pragma unroll
        for (int j = 0; j < 4; ++j)
            o_bf[(o << 8) + (i + j) * 4 + m] = f2bf(v[j]);
    }
}

// ------- fused stage 1+2: h = x@W^T+b (regs) -> t[b][i*4+m][y] ------------
// Double-buffered LDS + counted vmcnt(8); As/Bs XOR-swizzled (T2, both sides:
// pre-swizzled global source for linear gload_lds + swizzled ds_read addr).
__global__ __launch_bounds__(256, 2) void gemm_fused(
    const unsigned short* __restrict__ A,   // x_bf  [2048][4096]
    const unsigned short* __restrict__ B,   // w_bf  [4096][4096]
    const float* __restrict__ bias,
    const unsigned short* __restrict__ IT,  // innT [4][64][64][64] bf16, x pre-swizzled
    unsigned short* __restrict__ T)         // [2048][256][64] bf16
{
    // As0[0..8191] Bs0[..16383] As1[..24575] Bs1[..32767] | inn[32768..40959]
    // h tile (128x128=16384 elems) overlays As0+Bs0 after the main loop.
    __shared__ unsigned short smem[40960];  // 80 KB -> 2 blocks/CU
    unsigned short* inn = smem + 32768;

    const int tid = threadIdx.x;
    const int lane = tid & 63;
    const int w = tid >> 6;
    const int wm = w >> 1, wn = w & 1;
    int bx = blockIdx.x;
    bx = (bx & 7) * 64 + (bx >> 3);   // XCD swizzle: B panel 4MB = one L2
    const int m0 = (bx & 15) * 128;
    const int n0 = (bx >> 4) * 128;
    const int i0 = n0 >> 6;

    const int lr = lane & 15;
    const int hi = lane >> 4;
    const int lk = hi * 8;

    f32x4 acc[4][4] = {};

    // LDS[row][u] holds global (row, u ^ (row&7)); u = 16B unit 0..7 in a row
    auto STAGE = [&](int buf, int k0) {
        #pragma unroll
        for (int c = 0; c < 4; ++c) {
            int f = c * 2048 + tid * 8;
            int r = f >> 6;
            int colsw = ((((f >> 3) & 7) ^ (r & 7)) << 3);
            gload_lds16(A + (size_t)(m0 + r) * D_IN + k0 + colsw, smem + buf * 16384 + f);
            gload_lds16(B + (size_t)(n0 + r) * D_IN + k0 + colsw, smem + buf * 16384 + 8192 + f);
        }
    };
    auto COMPUTE = [&](int buf) {
        const unsigned short* as = smem + buf * 16384;
        const unsigned short* bs = as + 8192;
        #pragma unroll
        for (int kk = 0; kk < 2; ++kk) {
            short8 a[4], b[4];
            #pragma unroll
            for (int mi = 0; mi < 4; ++mi) {
                int row = wm * 64 + mi * 16 + lr;
                a[mi] = *(const short8*)(as + (row << 6) + ((((kk << 2) + hi) ^ (lr & 7)) << 3));
            }
            #pragma unroll
            for (int ni = 0; ni < 4; ++ni) {
                int row = wn * 64 + ni * 16 + lr;
                b[ni] = *(const short8*)(bs + (row << 6) + ((((kk << 2) + hi) ^ (lr & 7)) << 3));
            }
            #pragma unroll
            for (int mi = 0; mi < 4; ++mi)
                #pragma unroll
                for (int ni = 0; ni < 4; ++ni)   // swapped: D=[col][tok]
                    acc[mi][ni] = __builtin_amdgcn_mfma_f32_16x16x32_bf16(b[ni], a[mi], acc[mi][ni], 0, 0, 0);
        }
    };

    STAGE(0, 0);
    #pragma unroll 1
    for (int t = 0; t < 63; ++t) {
        STAGE((t + 1) & 1, (t + 1) * 64);
        asm volatile("s_waitcnt vmcnt(8)" ::: "memory");   // cur tile landed, next in flight
        __builtin_amdgcn_s_barrier();
        __builtin_amdgcn_sched_barrier(0);
        COMPUTE(t & 1);
        __builtin_amdgcn_s_barrier();                      // all reads done before next STAGE
        __builtin_amdgcn_sched_barrier(0);
    }
    asm volatile("s_waitcnt vmcnt(0)" ::: "memory");
    __builtin_amdgcn_s_barrier();
    __builtin_amdgcn_sched_barrier(0);
    COMPUTE(1);

    // ---- epilogue A: h (+bias, bf16) -> smem[0..16383], swizzled, US4 stores
    #pragma unroll
    for (int ni = 0; ni < 4; ++ni) {
        int col0 = wn * 64 + ni * 16 + hi * 4;
        f32x4 bv = *(const f32x4*)(bias + n0 + col0);
        #pragma unroll
        for (int mi = 0; mi < 4; ++mi) {
            int tok = wm * 64 + mi * 16 + lr;
            US4 o;
            #pragma unroll
            for (int j = 0; j < 4; ++j) o.v[j] = f2bf(acc[mi][ni][j] + bv[j]);
            *(US4*)(smem + tok * 128 + (col0 ^ ((tok & 7) << 3))) = o;
        }
    }

    // ---- epilogue B: per m, t[tok][(i0+wn)*4+m][y] = h[tok][i,:] @ innT^T
    for (int m = 0; m < 4; ++m) {
        #pragma unroll
        for (int c = 0; c < 4; ++c) {
            int e = c * 2048 + tid * 8;
            int i_loc = e >> 12, rem = e & 4095;
            gload_lds16(IT + ((size_t)(m * 64 + i0 + i_loc) << 12) + rem, inn + e);
        }
        asm volatile("s_waitcnt vmcnt(0)" ::: "memory");
        __syncthreads();   // inn ready; (m==0) h visible

        f32x4 acc2[4][4] = {};
        #pragma unroll
        for (int kk = 0; kk < 2; ++kk) {
            short8 a[4], b2[4];
            #pragma unroll
            for (int mi = 0; mi < 4; ++mi) {
                int tok = wm * 64 + mi * 16 + lr;
                a[mi] = *(const short8*)(smem + tok * 128 + ((wn * 64 + kk * 32 + lk) ^ ((tok & 7) << 3)));
            }
            #pragma unroll
            for (int ni = 0; ni < 4; ++ni) {
                int y = ni * 16 + lr;
                b2[ni] = *(const short8*)(inn + wn * 4096 + y * 64 + ((kk * 32 + lk) ^ ((y & 7) << 3)));
            }
            #pragma unroll
            for (int mi = 0; mi < 4; ++mi)
                #pragma unroll
                for (int ni = 0; ni < 4; ++ni)   // swapped: D=[y][tok]
                    acc2[mi][ni] = __builtin_amdgcn_mfma_f32_16x16x32_bf16(b2[ni], a[mi], acc2[mi][ni], 0, 0, 0);
        }

        const int kp = (i0 + wn) * 4 + m;
        #pragma unroll
        for (int mi = 0; mi < 4; ++mi) {
            int tok = m0 + wm * 64 + mi * 16 + lr;
            unsigned short* trow = T + ((size_t)tok * KMID + kp) * 64;
            #pragma unroll
            for (int ni = 0; ni < 4; ++ni) {
                int y0 = ni * 16 + hi * 4;
                US4 o;
                #pragma unroll
                for (int j = 0; j < 4; ++j) o.v[j] = f2bf(acc2[mi][ni][j]);
                *(US4*)(trow + y0) = o;
            }
        }
        __syncthreads();   // protect inn before next m's DMA
    }
}

// ---------------- stage 3: out[b][o][y] = sum_k outerB[o][k] * t[b][k][y] --
__global__ __launch_bounds__(512) void stage3(
    const unsigned short* __restrict__ T,   // [2048][256][64] bf16
    const unsigned short* __restrict__ Ob,  // [1024][256] bf16
    float* __restrict__ out)                // [2048][65536] f32
{
    __shared__ char ts[32768];
    const int tid = threadIdx.x;
    const int lane = tid & 63;
    const int w = tid >> 6;
    int bx = blockIdx.x;
    const int b = (bx & 7) * 256 + (bx >> 3);   // XCD swizzle
    const int lr = lane & 15;
    const int hi = lane >> 4;

    {
        const unsigned short* src = T + (size_t)b * (KMID * 64);
        #pragma unroll
        for (int c = 0; c < 4; ++c) {
            int e = c * 4096 + tid * 8;
            int k = e >> 6, y = e & 63;
            short8 v = __builtin_nontemporal_load((const short8*)(src + e));
            #pragma unroll
            for (int j = 0; j < 8; ++j)
                *(unsigned short*)(ts + SWZ(y + j, k)) = (unsigned short)v[j];
        }
    }
    __syncthreads();

    const int o_base = w * 128;
    f32x4 acc[4][8] = {};
    for (int kt = 0; kt < 8; ++kt) {
        short8 tf[4], of[8];
        #pragma unroll
        for (int ni = 0; ni < 4; ++ni)
            tf[ni] = *(const short8*)(ts + SWZ(ni * 16 + lr, kt * 32 + hi * 8));
        #pragma unroll
        for (int mi = 0; mi < 8; ++mi)
            of[mi] = *(const short8*)(Ob + ((size_t)(o_base + mi * 16 + lr) << 8) + kt * 32 + hi * 8);
        #pragma unroll
        for (int ni = 0; ni < 4; ++ni)
            #pragma unroll
            for (int mi = 0; mi < 8; ++mi)
                acc[ni][mi] = __builtin_amdgcn_mfma_f32_16x16x32_bf16(tf[ni], of[mi], acc[ni][mi], 0, 0, 0);
    }

    float* ob = out + (size_t)b * NUM_LATENTS;
    #pragma unroll
    for (int ni = 0; ni < 4; ++ni) {
        #pragma unroll
        for (int mi = 0; mi < 8; ++mi) {
            int o = o_base + mi * 16 + lr;
            int y = ni * 16 + hi * 4;
            __builtin_nontemporal_store(acc[ni][mi], (f32x4*)(ob + (o << 6) + y));
        }
    }
}

extern "C" void kernel_launch(void* const* d_in, const int* in_sizes, int n_in,
                              void* d_out, int out_size, void* d_ws, size_t ws_size,
                              hipStream_t stream) {
    const float* x     = (const float*)d_in[0];
    const float* pre_w = (const float*)d_in[1];
    const float* pre_b = (const float*)d_in[2];
    const float* inner = (const float*)d_in[3];
    const float* outer = (const float*)d_in[4];
    float* out = (float*)d_out;

    char* ws = (char*)d_ws;
    unsigned short* x_bf = (unsigned short*)ws;  ws += (size_t)TOKENS * D_IN * 2;
    unsigned short* w_bf = (unsigned short*)ws;  ws += (size_t)D_IN * D_IN * 2;
    unsigned short* o_bf = (unsigned short*)ws;  ws += (size_t)OUT_GROUPS * KMID * 2;
    unsigned short* t_bf = (unsigned short*)ws;  ws += (size_t)TOKENS * KMID * 64 * 2;
    unsigned short* it_bf = (unsigned short*)ws; ws += (size_t)GROUP_MUL * IN_GROUPS * 64 * 64 * 2;

    cvt_all<<<FLAT_BLOCKS + GROUP_MUL * IN_GROUPS, 256, 0, stream>>>(
        pre_w, x, outer, inner, w_bf, x_bf, o_bf, it_bf);

    gemm_fused<<<512, 256, 0, stream>>>(x_bf, w_bf, pre_b, it_bf, t_bf);
    stage3<<<2048, 512, 0, stream>>>(t_bf, o_bf, out);
}

// Round 7
// 313.269 us; speedup vs baseline: 1.2995x; 1.0056x over previous
//
#include <hip/hip_runtime.h>
#include <hip/hip_bf16.h>
#include <stdint.h>

#define D_IN 4096
#define TOKENS 2048
#define NUM_LATENTS 65536
#define GROUP_DIM 64
#define GROUP_MUL 4
#define IN_GROUPS 64
#define OUT_GROUPS 1024
#define KMID 256   // k' = i*4 + m

typedef __attribute__((ext_vector_type(8))) short short8;
typedef __attribute__((ext_vector_type(4))) float f32x4;

struct alignas(8)  US4 { unsigned short v[4]; };

#define FLAT_BLOCKS 24832   // (4194304 + 2097152 + 65536) / 256

__device__ inline unsigned short f2bf(float f) {
    union { float f; unsigned u; } w{f};
    unsigned r = w.u + 0x7fffu + ((w.u >> 16) & 1u);  // RNE
    return (unsigned short)(r >> 16);
}

__device__ inline void gload_lds16(const void* g, void* l) {
    __builtin_amdgcn_global_load_lds(
        (const __attribute__((address_space(1))) void*)g,
        (__attribute__((address_space(3))) void*)l, 16, 0, 0);
}

// stage3 LDS swizzle: [y][k] bf16 rows of 512B.
// XOR ((y&7)^((y>>3)&7)) into byte bits 4..6 -> 2-way (free) on BOTH the
// scalar write side (y0=(tid&7)*8, j=y&7) and the tf read side (y=ni*16+lr).
__device__ inline int SWZ(int y, int k) {
    return ((y << 9) + (k << 1)) ^ ((((y & 7) ^ ((y >> 3) & 7)) << 4));
}

// ------------- merged converts: w, x (vector), outer (perm), inner (transpose)
__global__ __launch_bounds__(256) void cvt_all(
    const float* __restrict__ w, const float* __restrict__ x,
    const float* __restrict__ outer, const float* __restrict__ inner,
    unsigned short* __restrict__ w_bf, unsigned short* __restrict__ x_bf,
    unsigned short* __restrict__ o_bf, unsigned short* __restrict__ it_bf) {
    __shared__ float tl[64][65];
    int blk = blockIdx.x;
    const int tid = threadIdx.x;
    if (blk >= FLAT_BLOCKS) {
        // inner[m][i][x][y] f32 -> innT[m][i][y][x^((y&7)<<3)] bf16 (pre-swizzled)
        blk -= FLAT_BLOCKS;                  // m*64+i
        const float* src = inner + (size_t)blk * 4096;
        #pragma unroll
        for (int p = 0; p < 4; ++p) {
            int idx = p * 1024 + tid * 4;
            int xx = idx >> 6, y = idx & 63;
            f32x4 v = *(const f32x4*)(src + idx);
            #pragma unroll
            for (int j = 0; j < 4; ++j) tl[xx][y + j] = v[j];
        }
        __syncthreads();
        unsigned short* dst = it_bf + (size_t)blk * 4096;
        #pragma unroll
        for (int p = 0; p < 4; ++p) {
            int idx = p * 1024 + tid * 4;
            int y = idx >> 6, x0 = idx & 63;
            US4 o;
            #pragma unroll
            for (int j = 0; j < 4; ++j) o.v[j] = f2bf(tl[x0 + j][y]);
            *(US4*)(dst + y * 64 + (x0 ^ ((y & 7) << 3))) = o;
        }
        return;
    }
    int s = blk * 256 + tid;                 // f32x4 slot
    if (s < 4194304) {                       // w
        f32x4 v = *(const f32x4*)(w + (size_t)s * 4);
        US4 o;
        #pragma unroll
        for (int j = 0; j < 4; ++j) o.v[j] = f2bf(v[j]);
        *(US4*)(w_bf + (size_t)s * 4) = o;
    } else if (s < 6291456) {                // x
        int t = s - 4194304;
        f32x4 v = *(const f32x4*)(x + (size_t)t * 4);
        US4 o;
        #pragma unroll
        for (int j = 0; j < 4; ++j) o.v[j] = f2bf(v[j]);
        *(US4*)(x_bf + (size_t)t * 4) = o;
    } else {                                 // outer: [o][m][i] -> [o][i*4+m]
        int t0 = (s - 6291456) * 4;
        int o = t0 >> 8, r = t0 & 255, m = r >> 6, i = r & 63;
        f32x4 v = *(const f32x4*)(outer + t0);
        #pragma unroll
        for (int j = 0; j < 4; ++j)
            o_bf[(o << 8) + (i + j) * 4 + m] = f2bf(v[j]);
    }
}

// ------- fused stage 1+2: h = x@W^T+b (regs) -> t[b][i*4+m][y] ------------
// Double-buffered LDS, ONE barrier per K-step (STAGE issued after the
// barrier -> T3-minimal schedule), counted overlap via end-of-phase vmcnt(0)
// on loads issued a full compute-phase earlier. T5 setprio around MFMAs.
__global__ __launch_bounds__(256, 2) void gemm_fused(
    const unsigned short* __restrict__ A,   // x_bf  [2048][4096]
    const unsigned short* __restrict__ B,   // w_bf  [4096][4096]
    const float* __restrict__ bias,
    const unsigned short* __restrict__ IT,  // innT [4][64][64][64] bf16, x pre-swizzled
    unsigned short* __restrict__ T)         // [2048][256][64] bf16
{
    // As0[0..8191] Bs0[..16383] As1[..24575] Bs1[..32767] | inn[32768..40959]
    // h tile (128x128=16384 elems) overlays As0+Bs0 after the main loop.
    __shared__ unsigned short smem[40960];  // 80 KB -> 2 blocks/CU
    unsigned short* inn = smem + 32768;

    const int tid = threadIdx.x;
    const int lane = tid & 63;
    const int w = tid >> 6;
    const int wm = w >> 1, wn = w & 1;
    int bx = blockIdx.x;
    bx = (bx & 7) * 64 + (bx >> 3);   // XCD swizzle: B panel 4MB = one L2
    const int m0 = (bx & 15) * 128;
    const int n0 = (bx >> 4) * 128;
    const int i0 = n0 >> 6;

    const int lr = lane & 15;
    const int hi = lane >> 4;
    const int lk = hi * 8;

    f32x4 acc[4][4] = {};

    // LDS[row][u] holds global (row, u ^ (row&7)); u = 16B unit 0..7 in a row
    auto STAGE = [&](int buf, int k0) {
        #pragma unroll
        for (int c = 0; c < 4; ++c) {
            int f = c * 2048 + tid * 8;
            int r = f >> 6;
            int colsw = ((((f >> 3) & 7) ^ (r & 7)) << 3);
            gload_lds16(A + (size_t)(m0 + r) * D_IN + k0 + colsw, smem + buf * 16384 + f);
            gload_lds16(B + (size_t)(n0 + r) * D_IN + k0 + colsw, smem + buf * 16384 + 8192 + f);
        }
    };
    auto COMPUTE = [&](int buf) {
        const unsigned short* as = smem + buf * 16384;
        const unsigned short* bs = as + 8192;
        #pragma unroll
        for (int kk = 0; kk < 2; ++kk) {
            short8 a[4], b[4];
            #pragma unroll
            for (int mi = 0; mi < 4; ++mi) {
                int row = wm * 64 + mi * 16 + lr;
                a[mi] = *(const short8*)(as + (row << 6) + ((((kk << 2) + hi) ^ (lr & 7)) << 3));
            }
            #pragma unroll
            for (int ni = 0; ni < 4; ++ni) {
                int row = wn * 64 + ni * 16 + lr;
                b[ni] = *(const short8*)(bs + (row << 6) + ((((kk << 2) + hi) ^ (lr & 7)) << 3));
            }
            __builtin_amdgcn_s_setprio(1);
            #pragma unroll
            for (int mi = 0; mi < 4; ++mi)
                #pragma unroll
                for (int ni = 0; ni < 4; ++ni)   // swapped: D=[col][tok]
                    acc[mi][ni] = __builtin_amdgcn_mfma_f32_16x16x32_bf16(b[ni], a[mi], acc[mi][ni], 0, 0, 0);
            __builtin_amdgcn_s_setprio(0);
        }
    };

    STAGE(0, 0);
    #pragma unroll 1
    for (int t = 0; t < 64; ++t) {
        // tile t's loads were issued one full compute-phase ago -> short wait
        asm volatile("s_waitcnt vmcnt(0)" ::: "memory");
        __builtin_amdgcn_s_barrier();
        __builtin_amdgcn_sched_barrier(0);
        if (t < 63) STAGE((t + 1) & 1, (t + 1) * 64);  // safe: buf^1's readers passed barrier
        COMPUTE(t & 1);
        __builtin_amdgcn_sched_barrier(0);
    }

    // ---- epilogue A: h (+bias, bf16) -> smem[0..16383], swizzled, US4 stores
    // (smem[0..16383] = buf0: its last readers finished before t=63's barrier)
    #pragma unroll
    for (int ni = 0; ni < 4; ++ni) {
        int col0 = wn * 64 + ni * 16 + hi * 4;
        f32x4 bv = *(const f32x4*)(bias + n0 + col0);
        #pragma unroll
        for (int mi = 0; mi < 4; ++mi) {
            int tok = wm * 64 + mi * 16 + lr;
            US4 o;
            #pragma unroll
            for (int j = 0; j < 4; ++j) o.v[j] = f2bf(acc[mi][ni][j] + bv[j]);
            *(US4*)(smem + tok * 128 + (col0 ^ ((tok & 7) << 3))) = o;
        }
    }

    // ---- epilogue B: per m, t[tok][(i0+wn)*4+m][y] = h[tok][i,:] @ innT^T
    for (int m = 0; m < 4; ++m) {
        #pragma unroll
        for (int c = 0; c < 4; ++c) {
            int e = c * 2048 + tid * 8;
            int i_loc = e >> 12, rem = e & 4095;
            gload_lds16(IT + ((size_t)(m * 64 + i0 + i_loc) << 12) + rem, inn + e);
        }
        asm volatile("s_waitcnt vmcnt(0)" ::: "memory");
        __syncthreads();   // inn ready; (m==0) h visible

        f32x4 acc2[4][4] = {};
        #pragma unroll
        for (int kk = 0; kk < 2; ++kk) {
            short8 a[4], b2[4];
            #pragma unroll
            for (int mi = 0; mi < 4; ++mi) {
                int tok = wm * 64 + mi * 16 + lr;
                a[mi] = *(const short8*)(smem + tok * 128 + ((wn * 64 + kk * 32 + lk) ^ ((tok & 7) << 3)));
            }
            #pragma unroll
            for (int ni = 0; ni < 4; ++ni) {
                int y = ni * 16 + lr;
                b2[ni] = *(const short8*)(inn + wn * 4096 + y * 64 + ((kk * 32 + lk) ^ ((y & 7) << 3)));
            }
            #pragma unroll
            for (int mi = 0; mi < 4; ++mi)
                #pragma unroll
                for (int ni = 0; ni < 4; ++ni)   // swapped: D=[y][tok]
                    acc2[mi][ni] = __builtin_amdgcn_mfma_f32_16x16x32_bf16(b2[ni], a[mi], acc2[mi][ni], 0, 0, 0);
        }

        const int kp = (i0 + wn) * 4 + m;
        #pragma unroll
        for (int mi = 0; mi < 4; ++mi) {
            int tok = m0 + wm * 64 + mi * 16 + lr;
            unsigned short* trow = T + ((size_t)tok * KMID + kp) * 64;
            #pragma unroll
            for (int ni = 0; ni < 4; ++ni) {
                int y0 = ni * 16 + hi * 4;
                US4 o;
                #pragma unroll
                for (int j = 0; j < 4; ++j) o.v[j] = f2bf(acc2[mi][ni][j]);
                *(US4*)(trow + y0) = o;
            }
        }
        __syncthreads();   // protect inn before next m's DMA
    }
}

// ---------------- stage 3: out[b][o][y] = sum_k outerB[o][k] * t[b][k][y] --
__global__ __launch_bounds__(512) void stage3(
    const unsigned short* __restrict__ T,   // [2048][256][64] bf16
    const unsigned short* __restrict__ Ob,  // [1024][256] bf16
    float* __restrict__ out)                // [2048][65536] f32
{
    __shared__ char ts[32768];
    const int tid = threadIdx.x;
    const int lane = tid & 63;
    const int w = tid >> 6;
    int bx = blockIdx.x;
    const int b = (bx & 7) * 256 + (bx >> 3);   // XCD swizzle
    const int lr = lane & 15;
    const int hi = lane >> 4;

    {
        const unsigned short* src = T + (size_t)b * (KMID * 64);
        #pragma unroll
        for (int c = 0; c < 4; ++c) {
            int e = c * 4096 + tid * 8;
            int k = e >> 6, y = e & 63;
            short8 v = __builtin_nontemporal_load((const short8*)(src + e));
            #pragma unroll
            for (int j = 0; j < 8; ++j)
                *(unsigned short*)(ts + SWZ(y + j, k)) = (unsigned short)v[j];
        }
    }
    __syncthreads();

    const int o_base = w * 128;
    f32x4 acc[4][8] = {};
    for (int kt = 0; kt < 8; ++kt) {
        short8 tf[4], of[8];
        #pragma unroll
        for (int ni = 0; ni < 4; ++ni)
            tf[ni] = *(const short8*)(ts + SWZ(ni * 16 + lr, kt * 32 + hi * 8));
        #pragma unroll
        for (int mi = 0; mi < 8; ++mi)
            of[mi] = *(const short8*)(Ob + ((size_t)(o_base + mi * 16 + lr) << 8) + kt * 32 + hi * 8);
        #pragma unroll
        for (int ni = 0; ni < 4; ++ni)
            #pragma unroll
            for (int mi = 0; mi < 8; ++mi)
                acc[ni][mi] = __builtin_amdgcn_mfma_f32_16x16x32_bf16(tf[ni], of[mi], acc[ni][mi], 0, 0, 0);
    }

    float* ob = out + (size_t)b * NUM_LATENTS;
    #pragma unroll
    for (int ni = 0; ni < 4; ++ni) {
        #pragma unroll
        for (int mi = 0; mi < 8; ++mi) {
            int o = o_base + mi * 16 + lr;
            int y = ni * 16 + hi * 4;
            __builtin_nontemporal_store(acc[ni][mi], (f32x4*)(ob + (o << 6) + y));
        }
    }
}

extern "C" void kernel_launch(void* const* d_in, const int* in_sizes, int n_in,
                              void* d_out, int out_size, void* d_ws, size_t ws_size,
                              hipStream_t stream) {
    const float* x     = (const float*)d_in[0];
    const float* pre_w = (const float*)d_in[1];
    const float* pre_b = (const float*)d_in[2];
    const float* inner = (const float*)d_in[3];
    const float* outer = (const float*)d_in[4];
    float* out = (float*)d_out;

    char* ws = (char*)d_ws;
    unsigned short* x_bf = (unsigned short*)ws;  ws += (size_t)TOKENS * D_IN * 2;
    unsigned short* w_bf = (unsigned short*)ws;  ws += (size_t)D_IN * D_IN * 2;
    unsigned short* o_bf = (unsigned short*)ws;  ws += (size_t)OUT_GROUPS * KMID * 2;
    unsigned short* t_bf = (unsigned short*)ws;  ws += (size_t)TOKENS * KMID * 64 * 2;
    unsigned short* it_bf = (unsigned short*)ws; ws += (size_t)GROUP_MUL * IN_GROUPS * 64 * 64 * 2;

    cvt_all<<<FLAT_BLOCKS + GROUP_MUL * IN_GROUPS, 256, 0, stream>>>(
        pre_w, x, outer, inner, w_bf, x_bf, o_bf, it_bf);

    gemm_fused<<<512, 256, 0, stream>>>(x_bf, w_bf, pre_b, it_bf, t_bf);
    stage3<<<2048, 512, 0, stream>>>(t_bf, o_bf, out);
}